// Round 2
// baseline (468.607 us; speedup 1.0000x reference)
//
#include <hip/hip_runtime.h>
#include <stdint.h>
#include <stddef.h>

typedef float f32x4 __attribute__((ext_vector_type(4)));
typedef __bf16 bf16x8 __attribute__((ext_vector_type(8)));

#define HH 96
#define MROWS 16
#define H1STRIDE 264   // bf16 elements; 132 dwords/row -> uniform 8 lanes/bank-group on b128 reads

__launch_bounds__(512, 2)
__global__ void policy_scan_kernel(
    const float* __restrict__ policy,     // (B,96,4)
    const float* __restrict__ noiseT,     // (B,96)  trans_noise
    const float* __restrict__ noiseD,     // (B,96)  demand_noise
    const float* __restrict__ action_pre, // (B,)
    const float* __restrict__ state_pre,  // (B,)
    const float* __restrict__ Lambda1,    // (1,)
    const float* __restrict__ Budget1,    // (1,)
    const float* __restrict__ W1,         // (256,6)
    const float* __restrict__ b1,         // (256,)
    const float* __restrict__ W2,         // (256,256)
    const float* __restrict__ b2,         // (256,)
    const float* __restrict__ W3,         // (256,)
    const float* __restrict__ b3,         // (1,)
    float* __restrict__ out)              // (B,96)
{
    __shared__ __attribute__((aligned(16))) float  featLDS[MROWS*HH*4];
    __shared__ __attribute__((aligned(16))) float  noiseTLDS[MROWS*HH];
    __shared__ __attribute__((aligned(16))) float  noiseDLDS[MROWS*HH];
    __shared__ __attribute__((aligned(16))) __bf16 h1hiLDS[MROWS*H1STRIDE];
    __shared__ __attribute__((aligned(16))) __bf16 h1loLDS[MROWS*H1STRIDE];
    __shared__ __attribute__((aligned(16))) float  partialLDS[8][MROWS];
    __shared__ float asLDS[MROWS][2];

    const int tid  = threadIdx.x;          // 0..511
    const int wave = tid >> 6;             // 0..7
    const int lane = tid & 63;
    const int l16  = lane & 15;
    const int lq   = lane >> 4;            // 0..3
    const int r0   = blockIdx.x * MROWS;

    // ---- stage per-block inputs into LDS (coalesced; block's slice is contiguous) ----
    {
        const f32x4* src = (const f32x4*)(policy + (size_t)r0 * HH * 4);
        f32x4* dst = (f32x4*)featLDS;
        #pragma unroll
        for (int i = 0; i < 3; ++i) dst[i*512 + tid] = src[i*512 + tid];
        if (tid < MROWS*HH/4) {
            ((f32x4*)noiseTLDS)[tid] = ((const f32x4*)(noiseT + (size_t)r0 * HH))[tid];
            ((f32x4*)noiseDLDS)[tid] = ((const f32x4*)(noiseD + (size_t)r0 * HH))[tid];
        }
    }

    // ---- W2 -> hi/lo bf16 B-fragments, register-resident for all 96 steps ----
    // B[k][n] = W2[n][k]; this lane holds n = (wave*2+nt)*16 + l16, k = kc*32 + lq*8 + j
    bf16x8 bhi[2][8], blo[2][8];
    float  b2v[2], w3v[2];
    #pragma unroll
    for (int nt = 0; nt < 2; ++nt) {
        const int n = (wave*2 + nt)*16 + l16;
        const float* wrow = W2 + (size_t)n * 256;
        #pragma unroll
        for (int kc = 0; kc < 8; ++kc) {
            const int k0 = kc*32 + lq*8;
            f32x4 u0 = *(const f32x4*)(wrow + k0);
            f32x4 u1 = *(const f32x4*)(wrow + k0 + 4);
            bf16x8 vh, vl;
            #pragma unroll
            for (int j = 0; j < 4; ++j) {
                __bf16 h0 = (__bf16)u0[j];
                __bf16 h1 = (__bf16)u1[j];
                vh[j]   = h0; vl[j]   = (__bf16)(u0[j] - (float)h0);
                vh[j+4] = h1; vl[j+4] = (__bf16)(u1[j] - (float)h1);
            }
            bhi[nt][kc] = vh;
            blo[nt][kc] = vl;
        }
        b2v[nt] = b2[n];
        w3v[nt] = W3[n];
    }

    // ---- layer-1 weights (fp32). neuron = tid&255; this thread covers 8 rows ----
    const int neuron = tid & 255;
    const int rbase  = (tid >> 8) * 8;     // rows 0-7 or 8-15
    const float w1r0 = W1[neuron*6+0], w1r1 = W1[neuron*6+1], w1r2 = W1[neuron*6+2];
    const float w1r3 = W1[neuron*6+3], w1r4 = W1[neuron*6+4], w1r5 = W1[neuron*6+5];
    const float b1s  = b1[neuron];

    const float lam  = Lambda1[0];
    const float budH = Budget1[0] / 96.0f;
    const float b3s  = b3[0];
    const float per_step = lam * 2.0f + budH;   // Lambda*D3 + Budget/Hn

    // ---- per-row recurrent state (threads 0..15 own one row each) ----
    float st_state = 0.f, st_bgt = 0.f, st_cumc = 0.f, st_S = 0.f, st_adprev = 0.f;
    if (tid < MROWS) {
        st_state  = state_pre[r0 + tid];
        st_bgt    = per_step;
        asLDS[tid][0] = action_pre[r0 + tid];
        asLDS[tid][1] = st_state;
    }
    __syncthreads();

    #pragma unroll 1
    for (int t = 0; t < HH; ++t) {
        // ---- Phase A: layer 1 (fp32), write hi/lo bf16 split of h1 ----
        #pragma unroll
        for (int ri = 0; ri < 8; ++ri) {
            const int row = rbase + ri;
            f32x4 f = *(const f32x4*)&featLDS[(row*HH + t)*4];   // broadcast
            float a = asLDS[row][0];
            float s = asLDS[row][1];
            float h = b1s;
            h = fmaf(w1r0, f[0], h); h = fmaf(w1r1, f[1], h);
            h = fmaf(w1r2, f[2], h); h = fmaf(w1r3, f[3], h);
            h = fmaf(w1r4, a,    h); h = fmaf(w1r5, s,    h);
            h = fmaxf(h, 0.0f);
            __bf16 hh = (__bf16)h;
            h1hiLDS[row*H1STRIDE + neuron] = hh;
            h1loLDS[row*H1STRIDE + neuron] = (__bf16)(h - (float)hh);
        }
        __syncthreads();

        // ---- Phase B: layer 2 = split-bf16 MFMA, 3 passes (hi*hi + hi*lo + lo*hi) ----
        bf16x8 ahi[8], alo[8];
        #pragma unroll
        for (int kc = 0; kc < 8; ++kc) {
            ahi[kc] = *(const bf16x8*)&h1hiLDS[l16*H1STRIDE + kc*32 + lq*8];
            alo[kc] = *(const bf16x8*)&h1loLDS[l16*H1STRIDE + kc*32 + lq*8];
        }
        f32x4 accA[2], accB[2];
        #pragma unroll
        for (int nt = 0; nt < 2; ++nt) { accA[nt] = f32x4{0,0,0,0}; accB[nt] = f32x4{0,0,0,0}; }
        #pragma unroll
        for (int kc = 0; kc < 8; ++kc) {
            #pragma unroll
            for (int nt = 0; nt < 2; ++nt) {
                accA[nt] = __builtin_amdgcn_mfma_f32_16x16x32_bf16(ahi[kc], bhi[nt][kc], accA[nt], 0, 0, 0);
                accB[nt] = __builtin_amdgcn_mfma_f32_16x16x32_bf16(ahi[kc], blo[nt][kc], accB[nt], 0, 0, 0);
            }
        }
        #pragma unroll
        for (int kc = 0; kc < 8; ++kc) {
            #pragma unroll
            for (int nt = 0; nt < 2; ++nt)
                accB[nt] = __builtin_amdgcn_mfma_f32_16x16x32_bf16(alo[kc], bhi[nt][kc], accB[nt], 0, 0, 0);
        }

        // ---- Phase C: bias+relu, dot with W3, reduce over n ----
        // acc[nt][r] = h2pre[m = lq*4+r][n = (wave*2+nt)*16 + l16]
        f32x4 p;
        #pragma unroll
        for (int r = 0; r < 4; ++r) {
            float v = 0.f;
            #pragma unroll
            for (int nt = 0; nt < 2; ++nt)
                v = fmaf(w3v[nt], fmaxf((accA[nt][r] + accB[nt][r]) + b2v[nt], 0.0f), v);
            p[r] = v;
        }
        #pragma unroll
        for (int m = 1; m < 16; m <<= 1) {
            p[0] += __shfl_xor(p[0], m);
            p[1] += __shfl_xor(p[1], m);
            p[2] += __shfl_xor(p[2], m);
            p[3] += __shfl_xor(p[3], m);
        }
        if (l16 == 0) *(f32x4*)&partialLDS[wave][lq*4] = p;
        __syncthreads();

        // ---- Phase D: per-row scalar recurrence (threads 0..15) ----
        if (tid < MROWS) {
            float psum = 0.f;
            #pragma unroll
            for (int w = 0; w < 8; ++w) psum += partialLDS[w][tid];
            float a_ml   = fmaxf(psum + b3s, 0.0f);
            float demand = featLDS[(tid*HH + t)*4];
            float nT     = noiseTLDS[tid*HH + t];
            float nD     = noiseDLDS[tid*HH + t];
            float ft     = 0.5f * (1.0f - __builtin_exp2f(-2.0f * (float)(95 - t)));
            float Gamma  = 2.0f + ft;                  // == gamma_list[t]
            float st_action = asLDS[tid][0]; (void)st_action;
            float a_prior = fminf(fmaxf(st_state + demand, 0.0f) * 1.25f, 10.0f);
            float sgn    = (a_ml < a_prior) ? 1.0f : -1.0f;
            float a_out  = fmaf(fmaxf(fabsf(a_ml - a_prior) - st_bgt / Gamma, 0.0f), sgn, a_ml);
            float ns     = fminf(fmaxf(st_state * (1.0f - nD) + demand - (0.8f + nT) * a_out, 0.0f), 15.0f);
            float c_cost = fmaf(fmaf(0.1f, ns, 1.0f), ns, 2.0f);    // D1*ns^2 + D2*ns + D3
            float ad_new = fabsf(a_out - a_prior);
            float cum_dv = fmaf(2.0f, ad_new, 0.375f * st_S);       // dev @ q_col
            float c_prior = fmaxf(2.0f, c_cost - cum_dv);
            float cum_c_new = st_cumc + (1.0f + lam) * c_prior - c_cost;
            float T      = fmaf(0.25f, st_S, ad_new);               // S_{t+1}
            float cum_dg = ft * T;                                  // dev @ g_col
            float bgt_if = fmaxf(fmaxf(st_bgt + per_step - ad_new * Gamma, 0.0f),
                                 cum_c_new - cum_dg + lam * 2.0f + budH * ((float)t + 2.0f));
            float bgt_else = fmaxf(st_bgt + per_step - st_adprev * Gamma, 0.0f);
            if (t == HH - 1) { st_bgt = bgt_else; }
            else             { st_bgt = bgt_if; st_cumc = cum_c_new; }
            st_S = T;
            st_adprev = ad_new;
            st_state  = ns;
            out[(size_t)(r0 + tid) * HH + t] = a_out;
            asLDS[tid][0] = a_out;
            asLDS[tid][1] = ns;
        }
        __syncthreads();
    }
}

extern "C" void kernel_launch(void* const* d_in, const int* in_sizes, int n_in,
                              void* d_out, int out_size, void* d_ws, size_t ws_size,
                              hipStream_t stream) {
    policy_scan_kernel<<<dim3(8192 / MROWS), dim3(512), 0, stream>>>(
        (const float*)d_in[0],  // policy_in_c
        (const float*)d_in[1],  // trans_noise
        (const float*)d_in[2],  // demand_noise
        (const float*)d_in[3],  // action_pre
        (const float*)d_in[4],  // state_pre
        (const float*)d_in[5],  // Lambda
        (const float*)d_in[6],  // Budget
        (const float*)d_in[7],  // W1
        (const float*)d_in[8],  // b1
        (const float*)d_in[9],  // W2
        (const float*)d_in[10], // b2
        (const float*)d_in[11], // W3
        (const float*)d_in[12], // b3
        (float*)d_out);
}